// Round 12
// baseline (106.344 us; speedup 1.0000x reference)
//
#include <hip/hip_runtime.h>

// EntityAttention — round 12: back half as a real dense GEMM.
// scores stores expS; sums computes inv = 1/sum(mask*expS) per (b,ent,h,e);
// outgemm: out = A @ VWt^T + bo with A = mask ? expS*inv : 0 built in LDS
// (128x128 tiles, dbuf A, K=1024 over 2 heads). Front half as R11.
// NB=8 SL=512 NH=512 EN=16 NE=64 HEADS=2 DH=256. Selection masks all-True.

#define NB 8
#define SL 512
#define NH 512
#define EN 16
#define NE 64
#define HEADS 2
#define DH 256
#define NSLOT (NB * EN)
#define SCALE 0.0625f

typedef __attribute__((ext_vector_type(8))) short short8;
typedef __attribute__((ext_vector_type(4))) short short4v;
typedef __attribute__((ext_vector_type(4))) float f32x4;

#define MFMA16(a, b, c) __builtin_amdgcn_mfma_f32_16x16x32_bf16(a, b, c, 0, 0, 0)

__device__ __forceinline__ short f2b(float f) {
    unsigned u = __builtin_bit_cast(unsigned, f);
    u += 0x7fffu + ((u >> 16) & 1u);
    return (short)(u >> 16);
}
__device__ __forceinline__ float b2f(short s) {
    return __builtin_bit_cast(float, ((unsigned)(unsigned short)s) << 16);
}
__device__ __forceinline__ int swz8(int hw, int chunk) {
    return (hw & 7) * chunk + (hw >> 3);
}

// ---- tiny GEMM helpers -----------------------------------------------------
__device__ __forceinline__ void ldg4(short8 (&d)[4], const short* p, int k, int stride) {
#pragma unroll
    for (int j = 0; j < 4; ++j) d[j] = *(const short8*)(p + (size_t)j * 16 * stride + k);
}
__device__ __forceinline__ void ldg2(short8 (&d)[2], const short* p, int k, int stride) {
#pragma unroll
    for (int j = 0; j < 2; ++j) d[j] = *(const short8*)(p + (size_t)j * 16 * stride + k);
}
__device__ __forceinline__ void mm44(f32x4 (&acc)[4][4], const short8 (&a)[4], const short8 (&bb)[4]) {
#pragma unroll
    for (int i = 0; i < 4; ++i)
#pragma unroll
        for (int j = 0; j < 4; ++j) acc[i][j] = MFMA16(a[i], bb[j], acc[i][j]);
}
__device__ __forceinline__ void mm42(f32x4 (&acc)[4][2], const short8 (&a)[4], const short8 (&bb)[2]) {
#pragma unroll
    for (int i = 0; i < 4; ++i)
#pragma unroll
        for (int j = 0; j < 2; ++j) acc[i][j] = MFMA16(a[i], bb[j], acc[i][j]);
}

// ---- ws byte offsets -------------------------------------------------------
#define WS_TOKS 0u
#define WS_K (4u << 20)
#define WS_V (8u << 20)
#define WS_S (20u << 20)
#define WS_WK (22u << 20)
#define WS_WV (WS_WK + (512u << 10))
#define WS_WO (WS_WV + (512u << 10))
#define WS_WQ (WS_WO + (512u << 10))
#define WS_EV (WS_WQ + (512u << 10))
#define WS_Q (WS_EV + (64u << 10))
#define WS_FLAG (WS_Q + (64u << 10))
#define WS_VW (24u << 20)  /* 8 MB */
#define WS_INV (32u << 20) /* 64 KB */

// chunk counts (f32x4 units) for prep
#define CH_TOKS (NB * SL * NH / 4)
#define CH_W (NH * NH / 4)
#define CH_EV (NE * NH / 4)
#define CH_TOTAL (CH_TOKS + 4 * CH_W + CH_EV)

// ---------------------------------------------------------------------------
__global__ void prep_kernel(const float* __restrict__ toks, const float* __restrict__ Wk,
                            const float* __restrict__ Wv, const float* __restrict__ Wo,
                            const float* __restrict__ Wq, const float* __restrict__ ev,
                            const unsigned char* __restrict__ ents,
                            short* __restrict__ toks_bf, short* __restrict__ Wk_bf,
                            short* __restrict__ Wv_bf, short* __restrict__ Wo_bf,
                            short* __restrict__ Wq_bf, short* __restrict__ ev_bf,
                            int* __restrict__ flag) {
    __shared__ int red[256];
    int idx = blockIdx.x * 256 + threadIdx.x;
    if (idx < CH_TOTAL) {
        const float* src;
        short* dst;
        int off = idx;
        if (idx < CH_TOKS) { src = toks; dst = toks_bf; }
        else if (idx < CH_TOKS + CH_W) { src = Wk; dst = Wk_bf; off -= CH_TOKS; }
        else if (idx < CH_TOKS + 2 * CH_W) { src = Wv; dst = Wv_bf; off -= CH_TOKS + CH_W; }
        else if (idx < CH_TOKS + 3 * CH_W) { src = Wo; dst = Wo_bf; off -= CH_TOKS + 2 * CH_W; }
        else if (idx < CH_TOKS + 4 * CH_W) { src = Wq; dst = Wq_bf; off -= CH_TOKS + 3 * CH_W; }
        else { src = ev; dst = ev_bf; off -= CH_TOKS + 4 * CH_W; }
        f32x4 v = ((const f32x4*)src)[off];
        short4v o;
#pragma unroll
        for (int j = 0; j < 4; ++j) o[j] = f2b(v[j]);
        ((short4v*)dst)[off] = o;
    }
    if (blockIdx.x == gridDim.x - 1) {
        int tid = threadIdx.x;
        int cnt = 0;
        for (int j = 0; j < 16; ++j) {
            int off = tid * 16 + j;
            if ((off & 3) != 0 && ents[off] != 0) cnt++;
        }
        red[tid] = cnt;
        __syncthreads();
        for (int s = 128; s > 0; s >>= 1) {
            if (tid < s) red[tid] += red[tid + s];
            __syncthreads();
        }
        if (tid == 0) flag[0] = (red[0] == 0) ? 1 : 0;
    }
}

// ---------------------------------------------------------------------------
// proj: K/V row-major + q. 128x128 tiles, 64x64/wave, 2-deep pipeline.
__global__ void __launch_bounds__(256, 2)
proj_kernel(const short* __restrict__ toks_bf,
            const short* __restrict__ Wk_bf,
            const short* __restrict__ Wv_bf,
            const short* __restrict__ ev_bf,
            const short* __restrict__ Wq_bf,
            const float* __restrict__ bk, const float* __restrict__ bv,
            const float* __restrict__ bq,
            short* __restrict__ K_bf, short* __restrict__ V_bf,
            short* __restrict__ q_bf) {
    int t = blockIdx.x;
    int tid = threadIdx.x, lane = tid & 63, wid = tid >> 6;
    int l15 = lane & 15;
    int kb = (lane >> 4) * 8;
    int crow = (lane >> 4) * 4;

    if (t < 256) {
        int l = swz8(t, 32);
        int b = l >> 5, kind = (l >> 4) & 1, mt = (l >> 2) & 3, nt = l & 3;
        int m0 = mt * 128 + (wid >> 1) * 64;
        int n0 = nt * 128 + (wid & 1) * 64;
        const short* A = toks_bf + ((size_t)b * SL + m0 + l15) * NH + kb;
        const short* B = (kind ? Wv_bf : Wk_bf) + (size_t)(n0 + l15) * NH + kb;
        const float* bias = kind ? bv : bk;
        short* dst = kind ? V_bf : K_bf;

        f32x4 acc[4][4];
#pragma unroll
        for (int i = 0; i < 4; ++i)
#pragma unroll
            for (int j = 0; j < 4; ++j) acc[i][j] = (f32x4)0.f;

        short8 a0[4], b0[4], a1[4], b1[4];
        ldg4(a0, A, 0, NH);
        ldg4(b0, B, 0, NH);
#pragma unroll
        for (int p = 0; p < 8; ++p) {
            int k1 = p * 64 + 32;
            ldg4(a1, A, k1, NH);
            ldg4(b1, B, k1, NH);
            mm44(acc, a0, b0);
            if (p < 7) {
                ldg4(a0, A, k1 + 32, NH);
                ldg4(b0, B, k1 + 32, NH);
            }
            mm44(acc, a1, b1);
        }

#pragma unroll
        for (int i = 0; i < 4; ++i) {
#pragma unroll
            for (int j = 0; j < 4; ++j) {
                int col = n0 + j * 16 + l15;
                float bval = bias[col];
                int row0 = m0 + i * 16 + crow;
#pragma unroll
                for (int r = 0; r < 4; ++r)
                    dst[((size_t)b * SL + row0 + r) * NH + col] = f2b(acc[i][j][r] + bval);
            }
        }
    } else {
        int tq = t - 256;
        int n0 = tq * 128 + wid * 32;
        const short* A = ev_bf + (size_t)l15 * NH + kb;
        const short* B = Wq_bf + (size_t)(n0 + l15) * NH + kb;

        f32x4 acc[4][2];
#pragma unroll
        for (int i = 0; i < 4; ++i)
#pragma unroll
            for (int j = 0; j < 2; ++j) acc[i][j] = (f32x4)0.f;

        for (int k = 0; k < NH; k += 32) {
            short8 a[4], bb[2];
#pragma unroll
            for (int i = 0; i < 4; ++i) a[i] = *(const short8*)(A + (size_t)i * 16 * NH + k);
#pragma unroll
            for (int j = 0; j < 2; ++j) bb[j] = *(const short8*)(B + (size_t)j * 16 * NH + k);
            mm42(acc, a, bb);
        }

#pragma unroll
        for (int i = 0; i < 4; ++i)
#pragma unroll
            for (int j = 0; j < 2; ++j) {
                int col = n0 + j * 16 + l15;
                float bval = bq[col];
#pragma unroll
                for (int r = 0; r < 4; ++r)
                    q_bf[(size_t)(i * 16 + crow + r) * NH + col] = f2b((acc[i][j][r] + bval) * SCALE);
            }
    }
}

// ---------------------------------------------------------------------------
// scores: S_bf[b][h][e][s] = EXP(q_scaled[e] . K[b][s]) in bf16. grid 64.
__global__ void __launch_bounds__(256, 2)
scores_mfma(const short* __restrict__ q_bf,
            const short* __restrict__ K_bf,
            short* __restrict__ S_bf) {
    int l = swz8(blockIdx.x, 8);
    int b = l >> 3, h = (l >> 2) & 1, st = l & 3;
    int tid = threadIdx.x, lane = tid & 63, wid = tid >> 6;
    int l15 = lane & 15;
    int n0 = st * 128 + wid * 32;
    int kb = (lane >> 4) * 8;

    f32x4 acc[4][2];
#pragma unroll
    for (int i = 0; i < 4; ++i)
#pragma unroll
        for (int j = 0; j < 2; ++j) acc[i][j] = (f32x4)0.f;

    const short* Aq = q_bf + (size_t)l15 * NH + h * DH + kb;
    const short* Bk = K_bf + ((size_t)b * SL + n0 + l15) * NH + h * DH + kb;

    short8 a0[4], a1[4];
    short8 b0[2], b1[2];
    ldg4(a0, Aq, 0, NH);
    ldg2(b0, Bk, 0, NH);
#pragma unroll
    for (int p = 0; p < 4; ++p) {
        int k1 = p * 64 + 32;
        ldg4(a1, Aq, k1, NH);
        ldg2(b1, Bk, k1, NH);
        mm42(acc, a0, b0);
        if (p < 3) {
            ldg4(a0, Aq, k1 + 32, NH);
            ldg2(b0, Bk, k1 + 32, NH);
        }
        mm42(acc, a1, b1);
    }

    int crow = (lane >> 4) * 4;
#pragma unroll
    for (int i = 0; i < 4; ++i)
#pragma unroll
        for (int j = 0; j < 2; ++j) {
            int col = n0 + j * 16 + l15;
#pragma unroll
            for (int r = 0; r < 4; ++r) {
                int row = i * 16 + crow + r;
                S_bf[(((size_t)(b * HEADS + h)) * NE + row) * SL + col] = f2b(__expf(acc[i][j][r]));
            }
        }
}

// ---------------------------------------------------------------------------
// vwt: VWt[b][h][o][s] = sum_d Wo[o][h*DH+d] * V[b][s][h*DH+d], bf16. grid 256.
__global__ void __launch_bounds__(256, 2)
vwt_kernel(const short* __restrict__ V_bf,
           const short* __restrict__ Wo_bf,
           short* __restrict__ VWt) {
    int l = swz8(blockIdx.x, 32);
    int bh = l >> 4, mt = (l >> 2) & 3, nt = l & 3;
    int b = bh >> 1, h = bh & 1;
    int tid = threadIdx.x, lane = tid & 63, wid = tid >> 6;
    int l15 = lane & 15;
    int kb = (lane >> 4) * 8;
    int crow = (lane >> 4) * 4;
    int m0 = mt * 128 + (wid >> 1) * 64;
    int n0 = nt * 128 + (wid & 1) * 64;

    const short* A = Wo_bf + (size_t)(m0 + l15) * NH + h * DH + kb;
    const short* B = V_bf + ((size_t)b * SL + n0 + l15) * NH + h * DH + kb;

    f32x4 acc[4][4];
#pragma unroll
    for (int i = 0; i < 4; ++i)
#pragma unroll
        for (int j = 0; j < 4; ++j) acc[i][j] = (f32x4)0.f;

    short8 a0[4], b0[4], a1[4], b1[4];
    ldg4(a0, A, 0, NH);
    ldg4(b0, B, 0, NH);
#pragma unroll
    for (int p = 0; p < 4; ++p) {
        int k1 = p * 64 + 32;
        ldg4(a1, A, k1, NH);
        ldg4(b1, B, k1, NH);
        mm44(acc, a0, b0);
        if (p < 3) {
            ldg4(a0, A, k1 + 32, NH);
            ldg4(b0, B, k1 + 32, NH);
        }
        mm44(acc, a1, b1);
    }

    short* dst = VWt + (size_t)bh * NH * SL;
#pragma unroll
    for (int i = 0; i < 4; ++i)
#pragma unroll
        for (int j = 0; j < 4; ++j) {
            int col = n0 + j * 16 + l15;
            int row0 = m0 + i * 16 + crow;
#pragma unroll
            for (int r = 0; r < 4; ++r)
                dst[(size_t)(row0 + r) * SL + col] = f2b(acc[i][j][r]);
        }
}

// ---------------------------------------------------------------------------
// sums: inv[b][ent][h][e] = 1 / sum_s mask[b,ent,s] * expS[b,h,e,s]. grid 256.
__global__ void __launch_bounds__(256, 4)
sums_kernel(const short* __restrict__ S_bf,
            const void* __restrict__ ents,
            const int* __restrict__ flag,
            float* __restrict__ inv) {
    __shared__ unsigned mask_lds[16];
    int l = swz8(blockIdx.x, 32); // b*32 + ent*2 + h
    int b = l >> 5, ent = (l >> 1) & 15, h = l & 1;
    int tid = threadIdx.x;
    if (tid < 16) {
        size_t base = ((size_t)b * EN + ent) * SL + tid * 32;
        unsigned m = 0;
        if (flag[0]) {
            const int* p = (const int*)ents;
            for (int j = 0; j < 32; ++j)
                if (p[base + j]) m |= 1u << j;
        } else {
            const unsigned char* p = (const unsigned char*)ents;
            for (int j = 0; j < 32; ++j)
                if (p[base + j]) m |= 1u << j;
        }
        mask_lds[tid] = m;
    }
    __syncthreads();
    int e = tid >> 2, part = tid & 3;
    const short* sp = S_bf + (((size_t)(b * HEADS + h)) * NE + e) * SL + part * 128;
    float s = 0.f;
#pragma unroll
    for (int c = 0; c < 16; ++c) {
        short8 v = *(const short8*)(sp + c * 8);
        int sidx = part * 128 + c * 8;
        unsigned mb = mask_lds[sidx >> 5] >> (sidx & 31);
#pragma unroll
        for (int j = 0; j < 8; ++j)
            if (mb >> j & 1) s += b2f(v[j]);
    }
    s += __shfl_xor(s, 1);
    s += __shfl_xor(s, 2);
    if (part == 0) inv[(((size_t)b * EN + ent) * HEADS + h) * NE + e] = 1.f / s;
}

// ---------------------------------------------------------------------------
// outgemm: out[b*1024 + ent*64 + e][o] = sum_kk A[row][kk]*VWt[b][h][o][s] + bo.
// A[ent_loc*64+e][kk] = mask[ent][s] ? expS[b,h,e,s]*inv[b,ent,h,e] : 0,
// kk = h*512 + s, built per 64-k-step into dbuf swizzled LDS.
// grid 256 = (b, mt(8), nt(4)) XCD-chunked; 256 thr, 4 waves of 64x64.
__global__ void __launch_bounds__(256, 2)
outgemm(const short* __restrict__ S_bf,
        const short* __restrict__ VWt,
        const void* __restrict__ ents,
        const int* __restrict__ flag,
        const float* __restrict__ inv,
        const float* __restrict__ bo,
        float* __restrict__ out) {
    __shared__ short Ald[2][128 * 64];   // 32 KB dbuf
    __shared__ unsigned mask_lds[2][16]; // 2 ents x 512 bits
    __shared__ float inv_lds[2][2][64];  // [ent_loc][h][e]

    int l = swz8(blockIdx.x, 32); // b*32 + mt*4 + nt
    int b = l >> 5, mt = (l >> 2) & 7, nt = l & 3;
    int tid = threadIdx.x, lane = tid & 63, wid = tid >> 6;
    int l15 = lane & 15, kb = (lane >> 4) * 8, crow = (lane >> 4) * 4;
    int wm = wid >> 1, wn = wid & 1;
    int ent0 = mt * 2;

    if (tid < 32) {
        int ei = tid >> 4, w = tid & 15;
        size_t base = ((size_t)b * EN + ent0 + ei) * SL + w * 32;
        unsigned m = 0;
        if (flag[0]) {
            const int* p = (const int*)ents;
            for (int j = 0; j < 32; ++j)
                if (p[base + j]) m |= 1u << j;
        } else {
            const unsigned char* p = (const unsigned char*)ents;
            for (int j = 0; j < 32; ++j)
                if (p[base + j]) m |= 1u << j;
        }
        mask_lds[ei][w] = m;
    }
    {
        int ei = tid >> 7, hh = (tid >> 6) & 1, ee = tid & 63;
        inv_lds[ei][hh][ee] = inv[(((size_t)b * EN + ent0 + ei) * HEADS + hh) * NE + ee];
    }
    __syncthreads();

    int ae = tid >> 2, aseg = (tid & 3) << 4; // e row, 16-elem s segment
    auto build = [&](int kk, int buf) {
        int h = kk >> 9, s0 = kk & 511;
        const short* sp = S_bf + (((size_t)(b * HEADS + h)) * NE + ae) * SL + s0 + aseg;
        short8 r0 = *(const short8*)sp;
        short8 r1 = *(const short8*)(sp + 8);
        int sbit = (s0 + aseg) & 31; // 0 or 16
        unsigned mword = (s0 + aseg) >> 5;
#pragma unroll
        for (int ei = 0; ei < 2; ++ei) {
            float iv = inv_lds[ei][h][ae];
            unsigned mbits = mask_lds[ei][mword] >> sbit;
            int row = ei * 64 + ae;
            short8 o0, o1;
#pragma unroll
            for (int j = 0; j < 8; ++j)
                o0[j] = (mbits >> j & 1) ? f2b(b2f(r0[j]) * iv) : (short)0;
#pragma unroll
            for (int j = 0; j < 8; ++j)
                o1[j] = (mbits >> (8 + j) & 1) ? f2b(b2f(r1[j]) * iv) : (short)0;
            short* base = &Ald[buf][row * 64];
            int g0 = aseg >> 3;
            *(short8*)&base[((g0 ^ (row & 7)) << 3)] = o0;
            *(short8*)&base[(((g0 + 1) ^ (row & 7)) << 3)] = o1;
        }
    };

    f32x4 acc[4][4];
#pragma unroll
    for (int i = 0; i < 4; ++i)
#pragma unroll
        for (int j = 0; j < 4; ++j) acc[i][j] = (f32x4)0.f;

    build(0, 0);
    __syncthreads();
    for (int p = 0; p < 16; ++p) {
        if (p < 15) build((p + 1) * 64, (p + 1) & 1);
        int h = (p * 64) >> 9, s0 = (p * 64) & 511;
        const short* Bw = VWt + ((size_t)(b * HEADS + h) * NH + nt * 128 + wn * 64 + l15) * SL + s0 + kb;
        const short* Abuf = Ald[p & 1];
#pragma unroll
        for (int sub = 0; sub < 2; ++sub) {
            short8 av[4], bv[4];
            int g = (sub * 32 + kb) >> 3;
#pragma unroll
            for (int i = 0; i < 4; ++i) {
                int row = wm * 64 + i * 16 + l15;
                av[i] = *(const short8*)&Abuf[row * 64 + ((g ^ (row & 7)) << 3)];
            }
            ldg4(bv, Bw, sub * 32, SL);
            mm44(acc, av, bv);
        }
        __syncthreads();
    }

    // epilogue
    int gr0 = b * 1024 + mt * 128 + wm * 64;
#pragma unroll
    for (int i = 0; i < 4; ++i)
#pragma unroll
        for (int j = 0; j < 4; ++j) {
            int col = nt * 128 + wn * 64 + j * 16 + l15;
            float bval = bo[col];
#pragma unroll
            for (int r = 0; r < 4; ++r) {
                int row = gr0 + i * 16 + crow + r;
                out[(size_t)row * NH + col] = acc[i][j][r] + bval;
            }
        }
}

// ---------------------------------------------------------------------------
extern "C" void kernel_launch(void* const* d_in, const int* in_sizes, int n_in,
                              void* d_out, int out_size, void* d_ws, size_t ws_size,
                              hipStream_t stream) {
    const float* toks = (const float*)d_in[0];
    const void* ents = d_in[1];
    const float* evs = (const float*)d_in[2];
    const float* Wq = (const float*)d_in[6];
    const float* Wk = (const float*)d_in[7];
    const float* Wv = (const float*)d_in[8];
    const float* bq = (const float*)d_in[9];
    const float* bk = (const float*)d_in[10];
    const float* bv = (const float*)d_in[11];
    const float* Wo = (const float*)d_in[12];
    const float* bo = (const float*)d_in[13];

    char* ws = (char*)d_ws;
    short* toks_bf = (short*)(ws + WS_TOKS);
    short* K_bf = (short*)(ws + WS_K);
    short* V_bf = (short*)(ws + WS_V);
    short* S_bf = (short*)(ws + WS_S);
    short* Wk_bf = (short*)(ws + WS_WK);
    short* Wv_bf = (short*)(ws + WS_WV);
    short* Wo_bf = (short*)(ws + WS_WO);
    short* Wq_bf = (short*)(ws + WS_WQ);
    short* ev_bf = (short*)(ws + WS_EV);
    short* q_bf = (short*)(ws + WS_Q);
    int* flag = (int*)(ws + WS_FLAG);
    short* VWt = (short*)(ws + WS_VW);
    float* inv = (float*)(ws + WS_INV);

    prep_kernel<<<CH_TOTAL / 256 + 1, 256, 0, stream>>>(
        toks, Wk, Wv, Wo, Wq, evs, (const unsigned char*)ents,
        toks_bf, Wk_bf, Wv_bf, Wo_bf, Wq_bf, ev_bf, flag);
    proj_kernel<<<260, 256, 0, stream>>>(toks_bf, Wk_bf, Wv_bf, ev_bf, Wq_bf,
                                         bk, bv, bq, K_bf, V_bf, q_bf);
    scores_mfma<<<64, 256, 0, stream>>>(q_bf, K_bf, S_bf);
    vwt_kernel<<<256, 256, 0, stream>>>(V_bf, Wo_bf, VWt);
    sums_kernel<<<256, 256, 0, stream>>>(S_bf, ents, flag, inv);
    outgemm<<<256, 256, 0, stream>>>(S_bf, VWt, ents, flag, inv, bo, (float*)d_out);
}

// Round 13
// 84.825 us; speedup vs baseline: 1.2537x; 1.2537x over previous
//
#include <hip/hip_runtime.h>

// EntityAttention — round 13: R10 base (proven 85.2 µs), single change:
// attn_out 8 waves -> 16 waves (1024 thr, 4 waves/SIMD) for 2x TLP.
// NB=8 SL=512 NH=512 EN=16 NE=64 HEADS=2 DH=256. Selection masks all-True.

#define NB 8
#define SL 512
#define NH 512
#define EN 16
#define NE 64
#define HEADS 2
#define DH 256
#define NSLOT (NB * EN)
#define SCALE 0.0625f

typedef __attribute__((ext_vector_type(8))) short short8;
typedef __attribute__((ext_vector_type(4))) short short4v;
typedef __attribute__((ext_vector_type(4))) float f32x4;

#define MFMA16(a, b, c) __builtin_amdgcn_mfma_f32_16x16x32_bf16(a, b, c, 0, 0, 0)

__device__ __forceinline__ short f2b(float f) {
    unsigned u = __builtin_bit_cast(unsigned, f);
    u += 0x7fffu + ((u >> 16) & 1u);
    return (short)(u >> 16);
}
__device__ __forceinline__ float b2f(short s) {
    return __builtin_bit_cast(float, ((unsigned)(unsigned short)s) << 16);
}
__device__ __forceinline__ int swz8(int hw, int chunk) {
    return (hw & 7) * chunk + (hw >> 3);
}

// ---- tiny GEMM helpers -----------------------------------------------------
__device__ __forceinline__ void ldg4(short8 (&d)[4], const short* p, int k, int stride) {
#pragma unroll
    for (int j = 0; j < 4; ++j) d[j] = *(const short8*)(p + (size_t)j * 16 * stride + k);
}
__device__ __forceinline__ void ldg2(short8 (&d)[2], const short* p, int k, int stride) {
#pragma unroll
    for (int j = 0; j < 2; ++j) d[j] = *(const short8*)(p + (size_t)j * 16 * stride + k);
}
__device__ __forceinline__ void ldsw2(short8 (&d)[2], const short* Ph, int k, int kb, int l15) {
    int g = (k + kb) >> 3;
#pragma unroll
    for (int i = 0; i < 2; ++i) {
        int el = i * 16 + l15;
        d[i] = *(const short8*)&Ph[el * SL + ((g ^ (el & 7)) * 8)];
    }
}
__device__ __forceinline__ void mm44(f32x4 (&acc)[4][4], const short8 (&a)[4], const short8 (&bb)[4]) {
#pragma unroll
    for (int i = 0; i < 4; ++i)
#pragma unroll
        for (int j = 0; j < 4; ++j) acc[i][j] = MFMA16(a[i], bb[j], acc[i][j]);
}
__device__ __forceinline__ void mm42(f32x4 (&acc)[4][2], const short8 (&a)[4], const short8 (&bb)[2]) {
#pragma unroll
    for (int i = 0; i < 4; ++i)
#pragma unroll
        for (int j = 0; j < 2; ++j) acc[i][j] = MFMA16(a[i], bb[j], acc[i][j]);
}
__device__ __forceinline__ void mm22(f32x4 (&acc)[2][2], const short8 (&a)[2], const short8 (&bb)[2]) {
#pragma unroll
    for (int i = 0; i < 2; ++i)
#pragma unroll
        for (int j = 0; j < 2; ++j) acc[i][j] = MFMA16(a[i], bb[j], acc[i][j]);
}

// ---- ws byte offsets (no aliasing) -----------------------------------------
#define WS_TOKS 0u
#define WS_K (4u << 20)
#define WS_VT (8u << 20)
#define WS_S (20u << 20)
#define WS_WK (22u << 20)
#define WS_WV (WS_WK + (512u << 10))
#define WS_WO (WS_WV + (512u << 10))
#define WS_WQ (WS_WO + (512u << 10))
#define WS_EV (WS_WQ + (512u << 10))
#define WS_Q (WS_EV + (64u << 10))
#define WS_FLAG (WS_Q + (64u << 10))

// chunk counts (f32x4 units) for prep
#define CH_TOKS (NB * SL * NH / 4)
#define CH_W (NH * NH / 4)
#define CH_EV (NE * NH / 4)
#define CH_TOTAL (CH_TOKS + 4 * CH_W + CH_EV)

// ---------------------------------------------------------------------------
__global__ void prep_kernel(const float* __restrict__ toks, const float* __restrict__ Wk,
                            const float* __restrict__ Wv, const float* __restrict__ Wo,
                            const float* __restrict__ Wq, const float* __restrict__ ev,
                            const unsigned char* __restrict__ ents,
                            short* __restrict__ toks_bf, short* __restrict__ Wk_bf,
                            short* __restrict__ Wv_bf, short* __restrict__ Wo_bf,
                            short* __restrict__ Wq_bf, short* __restrict__ ev_bf,
                            int* __restrict__ flag) {
    __shared__ int red[256];
    int idx = blockIdx.x * 256 + threadIdx.x;
    if (idx < CH_TOTAL) {
        const float* src;
        short* dst;
        int off = idx;
        if (idx < CH_TOKS) { src = toks; dst = toks_bf; }
        else if (idx < CH_TOKS + CH_W) { src = Wk; dst = Wk_bf; off -= CH_TOKS; }
        else if (idx < CH_TOKS + 2 * CH_W) { src = Wv; dst = Wv_bf; off -= CH_TOKS + CH_W; }
        else if (idx < CH_TOKS + 3 * CH_W) { src = Wo; dst = Wo_bf; off -= CH_TOKS + 2 * CH_W; }
        else if (idx < CH_TOKS + 4 * CH_W) { src = Wq; dst = Wq_bf; off -= CH_TOKS + 3 * CH_W; }
        else { src = ev; dst = ev_bf; off -= CH_TOKS + 4 * CH_W; }
        f32x4 v = ((const f32x4*)src)[off];
        short4v o;
#pragma unroll
        for (int j = 0; j < 4; ++j) o[j] = f2b(v[j]);
        ((short4v*)dst)[off] = o;
    }
    if (blockIdx.x == gridDim.x - 1) {
        int tid = threadIdx.x;
        int cnt = 0;
        for (int j = 0; j < 16; ++j) {
            int off = tid * 16 + j;
            if ((off & 3) != 0 && ents[off] != 0) cnt++;
        }
        red[tid] = cnt;
        __syncthreads();
        for (int s = 128; s > 0; s >>= 1) {
            if (tid < s) red[tid] += red[tid + s];
            __syncthreads();
        }
        if (tid == 0) flag[0] = (red[0] == 0) ? 1 : 0;
    }
}

// ---------------------------------------------------------------------------
// proj: hw<256: K/V tiles (XCD-chunked); hw>=256: q. 128x128 tiles, 64x64/wave.
__global__ void __launch_bounds__(256, 2)
proj_kernel(const short* __restrict__ toks_bf,
            const short* __restrict__ Wk_bf,
            const short* __restrict__ Wv_bf,
            const short* __restrict__ ev_bf,
            const short* __restrict__ Wq_bf,
            const float* __restrict__ bk, const float* __restrict__ bv,
            const float* __restrict__ bq,
            short* __restrict__ K_bf, short* __restrict__ Vt_bf,
            short* __restrict__ q_bf) {
    int t = blockIdx.x;
    int tid = threadIdx.x, lane = tid & 63, wid = tid >> 6;
    int l15 = lane & 15;
    int kb = (lane >> 4) * 8;
    int crow = (lane >> 4) * 4;

    if (t < 256) {
        int l = swz8(t, 32);
        int b = l >> 5, kind = (l >> 4) & 1, mt = (l >> 2) & 3, nt = l & 3;
        int m0 = mt * 128 + (wid >> 1) * 64;
        int n0 = nt * 128 + (wid & 1) * 64;
        const short* A = toks_bf + ((size_t)b * SL + m0 + l15) * NH + kb;
        const short* B = (kind ? Wv_bf : Wk_bf) + (size_t)(n0 + l15) * NH + kb;
        const float* bias = kind ? bv : bk;

        f32x4 acc[4][4];
#pragma unroll
        for (int i = 0; i < 4; ++i)
#pragma unroll
            for (int j = 0; j < 4; ++j) acc[i][j] = (f32x4)0.f;

        short8 a0[4], b0[4], a1[4], b1[4];
        ldg4(a0, A, 0, NH);
        ldg4(b0, B, 0, NH);
#pragma unroll
        for (int p = 0; p < 8; ++p) {
            int k1 = p * 64 + 32;
            ldg4(a1, A, k1, NH);
            ldg4(b1, B, k1, NH);
            mm44(acc, a0, b0);
            if (p < 7) {
                ldg4(a0, A, k1 + 32, NH);
                ldg4(b0, B, k1 + 32, NH);
            }
            mm44(acc, a1, b1);
        }

#pragma unroll
        for (int i = 0; i < 4; ++i) {
#pragma unroll
            for (int j = 0; j < 4; ++j) {
                int col = n0 + j * 16 + l15;
                float bval = bias[col];
                int row0 = m0 + i * 16 + crow;
                if (kind == 0) {
#pragma unroll
                    for (int r = 0; r < 4; ++r)
                        K_bf[((size_t)b * SL + row0 + r) * NH + col] = f2b(acc[i][j][r] + bval);
                } else {
                    short4v pack;
#pragma unroll
                    for (int r = 0; r < 4; ++r) pack[r] = f2b(acc[i][j][r] + bval);
                    *(short4v*)(Vt_bf + ((size_t)b * NH + col) * SL + row0) = pack;
                }
            }
        }
    } else {
        int tq = t - 256;
        int n0 = tq * 128 + wid * 32;
        const short* A = ev_bf + (size_t)l15 * NH + kb;
        const short* B = Wq_bf + (size_t)(n0 + l15) * NH + kb;

        f32x4 acc[4][2];
#pragma unroll
        for (int i = 0; i < 4; ++i)
#pragma unroll
            for (int j = 0; j < 2; ++j) acc[i][j] = (f32x4)0.f;

        for (int k = 0; k < NH; k += 32) {
            short8 a[4], bb[2];
#pragma unroll
            for (int i = 0; i < 4; ++i) a[i] = *(const short8*)(A + (size_t)i * 16 * NH + k);
#pragma unroll
            for (int j = 0; j < 2; ++j) bb[j] = *(const short8*)(B + (size_t)j * 16 * NH + k);
            mm42(acc, a, bb);
        }

#pragma unroll
        for (int i = 0; i < 4; ++i)
#pragma unroll
            for (int j = 0; j < 2; ++j) {
                int col = n0 + j * 16 + l15;
                float bval = bq[col];
#pragma unroll
                for (int r = 0; r < 4; ++r)
                    q_bf[(size_t)(i * 16 + crow + r) * NH + col] = f2b((acc[i][j][r] + bval) * SCALE);
            }
    }
}

// ---------------------------------------------------------------------------
// scores: S_bf[b][h][e][s] = q_scaled[e] . K[b][s] (bf16 out). grid 64.
__global__ void __launch_bounds__(256, 2)
scores_mfma(const short* __restrict__ q_bf,
            const short* __restrict__ K_bf,
            short* __restrict__ S_bf) {
    int l = swz8(blockIdx.x, 8);
    int b = l >> 3, h = (l >> 2) & 1, st = l & 3;
    int tid = threadIdx.x, lane = tid & 63, wid = tid >> 6;
    int l15 = lane & 15;
    int n0 = st * 128 + wid * 32;
    int kb = (lane >> 4) * 8;

    f32x4 acc[4][2];
#pragma unroll
    for (int i = 0; i < 4; ++i)
#pragma unroll
        for (int j = 0; j < 2; ++j) acc[i][j] = (f32x4)0.f;

    const short* Aq = q_bf + (size_t)l15 * NH + h * DH + kb;
    const short* Bk = K_bf + ((size_t)b * SL + n0 + l15) * NH + h * DH + kb;

    short8 a0[4], a1[4];
    short8 b0[2], b1[2];
    ldg4(a0, Aq, 0, NH);
    ldg2(b0, Bk, 0, NH);
#pragma unroll
    for (int p = 0; p < 4; ++p) {
        int k1 = p * 64 + 32;
        ldg4(a1, Aq, k1, NH);
        ldg2(b1, Bk, k1, NH);
        mm42(acc, a0, b0);
        if (p < 3) {
            ldg4(a0, Aq, k1 + 32, NH);
            ldg2(b0, Bk, k1 + 32, NH);
        }
        mm42(acc, a1, b1);
    }

    int crow = (lane >> 4) * 4;
#pragma unroll
    for (int i = 0; i < 4; ++i)
#pragma unroll
        for (int j = 0; j < 2; ++j) {
            int col = n0 + j * 16 + l15;
#pragma unroll
            for (int r = 0; r < 4; ++r) {
                int row = i * 16 + crow + r;
                S_bf[(((size_t)(b * HEADS + h)) * NE + row) * SL + col] = f2b(acc[i][j][r]);
            }
        }
}

// ---------------------------------------------------------------------------
// attn_out: softmax -> PV -> out-GEMM fused. Block = (slot n, e-half eh),
// 1024 thr (16 waves = 4/SIMD). Per-wave tiles are 32 wide: PV wave =
// (h = w>>3, dq8 = w&7) rows 32 x cols 32; out wave = cols w*32..+32.
// Softmax no-max; 2-deep pipelined k-loops; cross-phase prefetch.
__global__ void __launch_bounds__(1024, 2)
attn_out(const short* __restrict__ S_bf,
         const short* __restrict__ Vt_bf,
         const void* __restrict__ ents,
         const int* __restrict__ flag,
         const short* __restrict__ Wo_bf,
         const float* __restrict__ bo,
         float* __restrict__ out) {
    __shared__ short Pld[2 * 32 * SL]; // 64 KB
    int l = swz8(blockIdx.x, 32); // b*32 + ent*2 + eh
    int b = l >> 5;
    int ent = (l >> 1) & 15, eh = l & 1;
    int n = b * EN + ent;
    int tid = threadIdx.x, lane = tid & 63, wid = tid >> 6; // wid 0..15
    int l15 = lane & 15;
    int kb = (lane >> 4) * 8;
    int crow = (lane >> 4) * 4;
    int h = wid >> 3, sub8 = wid & 7;

    // key-padding mask bits for s = lane*8 + j
    unsigned att8 = 0;
    {
        size_t mbase = ((size_t)b * EN + ent) * SL + lane * 8;
        if (flag[0]) {
            const int* p = (const int*)ents;
#pragma unroll
            for (int j = 0; j < 8; ++j)
                if (p[mbase + j]) att8 |= 1u << j;
        } else {
            const unsigned char* p = (const unsigned char*)ents;
#pragma unroll
            for (int j = 0; j < 8; ++j)
                if (p[mbase + j]) att8 |= 1u << j;
        }
    }

    // ---- early prefetch: PV iter-0 V loads ----
    const short* Bv = Vt_bf + ((size_t)b * NH + h * DH + sub8 * 32 + l15) * SL + kb;
    short8 bvA[2], bvB[2];
    ldg2(bvA, Bv, 0, SL);
    __builtin_amdgcn_sched_barrier(0);

    // ---- Phase A: softmax (no max). wave w: head h, rows el = sub8*4..+4 ----
    {
        const short* Sbase =
            S_bf + (((size_t)(b * HEADS + h)) * NE + eh * 32 + sub8 * 4) * SL + lane * 8;
        short8 sr[4];
#pragma unroll
        for (int it = 0; it < 4; ++it) sr[it] = *(const short8*)(Sbase + (size_t)it * SL);

        float pall[4][8];
        float sums[4];
#pragma unroll
        for (int it = 0; it < 4; ++it) {
            float s = 0.f;
#pragma unroll
            for (int j = 0; j < 8; ++j) {
                float v = (att8 >> j & 1) ? b2f(sr[it][j]) : -1e9f;
                float e = __expf(v);
                pall[it][j] = e;
                s += e;
            }
            sums[it] = s;
        }
#pragma unroll
        for (int off = 32; off; off >>= 1)
#pragma unroll
            for (int it = 0; it < 4; ++it) sums[it] += __shfl_xor(sums[it], off);
#pragma unroll
        for (int it = 0; it < 4; ++it) {
            float iv = 1.f / sums[it];
            short8 pv;
#pragma unroll
            for (int j = 0; j < 8; ++j) pv[j] = f2b(pall[it][j] * iv);
            int el = sub8 * 4 + it;
            *(short8*)&Pld[h * (32 * SL) + el * SL + ((lane ^ (el & 7)) * 8)] = pv;
        }
    }
    __syncthreads();

    // ---- Phase B: PV, 2-deep pipelined. wave (h, sub8): 32 rows x 32 cols ----
    f32x4 acc[2][2];
#pragma unroll
    for (int i = 0; i < 2; ++i)
#pragma unroll
        for (int j = 0; j < 2; ++j) acc[i][j] = (f32x4)0.f;
    {
        const short* Ph = &Pld[h * (32 * SL)];
        short8 paA[2], paB[2];
        ldsw2(paA, Ph, 0, kb, l15);
#pragma unroll
        for (int p = 0; p < 8; ++p) {
            int k1 = p * 64 + 32;
            ldg2(bvB, Bv, k1, SL);
            ldsw2(paB, Ph, k1, kb, l15);
            mm22(acc, paA, bvA);
            if (p < 7) {
                ldg2(bvA, Bv, k1 + 32, SL);
                ldsw2(paA, Ph, k1 + 32, kb, l15);
            }
            mm22(acc, paB, bvB);
        }
    }
    __syncthreads();

    // ---- early prefetch: out-GEMM iter-0 Wo loads ----
    const short* Bw = Wo_bf + (size_t)(wid * 32 + l15) * NH + kb;
    short8 bwA[2], bwB[2];
    ldg2(bwA, Bw, 0, NH);
    __builtin_amdgcn_sched_barrier(0);

    // ---- Phase C: ctx -> LDS (reuse lower 32 KB) ----
#pragma unroll
    for (int i = 0; i < 2; ++i)
#pragma unroll
        for (int j = 0; j < 2; ++j) {
            int dg = h * DH + sub8 * 32 + j * 16 + l15; // 0..511
            int g = dg >> 3, cs = dg & 7;
#pragma unroll
            for (int r = 0; r < 4; ++r) {
                int el = i * 16 + crow + r;
                Pld[el * SL + ((g ^ (el & 7)) * 8) + cs] = f2b(acc[i][j][r]);
            }
        }
    __syncthreads();

    // ---- Phase D: out tile [32 x 512]; wave w: cols w*32..+32 ----
    {
        f32x4 oacc[2][2];
#pragma unroll
        for (int i = 0; i < 2; ++i)
#pragma unroll
            for (int j = 0; j < 2; ++j) oacc[i][j] = (f32x4)0.f;

        short8 caA[2], caB[2];
        ldsw2(caA, Pld, 0, kb, l15);
#pragma unroll
        for (int p = 0; p < 8; ++p) {
            int k1 = p * 64 + 32;
            ldg2(bwB, Bw, k1, NH);
            ldsw2(caB, Pld, k1, kb, l15);
            mm22(oacc, caA, bwA);
            if (p < 7) {
                ldg2(bwA, Bw, k1 + 32, NH);
                ldsw2(caA, Pld, k1 + 32, kb, l15);
            }
            mm22(oacc, caB, bwB);
        }

        size_t rbase = (size_t)n * NE + eh * 32;
#pragma unroll
        for (int i = 0; i < 2; ++i)
#pragma unroll
            for (int j = 0; j < 2; ++j) {
                int col = wid * 32 + j * 16 + l15;
                float bval = bo[col];
#pragma unroll
                for (int r = 0; r < 4; ++r) {
                    size_t row = rbase + i * 16 + crow + r;
                    out[row * NH + col] = oacc[i][j][r] + bval;
                }
            }
    }
}

// ---------------------------------------------------------------------------
extern "C" void kernel_launch(void* const* d_in, const int* in_sizes, int n_in,
                              void* d_out, int out_size, void* d_ws, size_t ws_size,
                              hipStream_t stream) {
    const float* toks = (const float*)d_in[0];
    const void* ents = d_in[1];
    const float* evs = (const float*)d_in[2];
    const float* Wq = (const float*)d_in[6];
    const float* Wk = (const float*)d_in[7];
    const float* Wv = (const float*)d_in[8];
    const float* bq = (const float*)d_in[9];
    const float* bk = (const float*)d_in[10];
    const float* bv = (const float*)d_in[11];
    const float* Wo = (const float*)d_in[12];
    const float* bo = (const float*)d_in[13];

    char* ws = (char*)d_ws;
    short* toks_bf = (short*)(ws + WS_TOKS);
    short* K_bf = (short*)(ws + WS_K);
    short* Vt_bf = (short*)(ws + WS_VT);
    short* S_bf = (short*)(ws + WS_S);
    short* Wk_bf = (short*)(ws + WS_WK);
    short* Wv_bf = (short*)(ws + WS_WV);
    short* Wo_bf = (short*)(ws + WS_WO);
    short* Wq_bf = (short*)(ws + WS_WQ);
    short* ev_bf = (short*)(ws + WS_EV);
    short* q_bf = (short*)(ws + WS_Q);
    int* flag = (int*)(ws + WS_FLAG);

    prep_kernel<<<CH_TOTAL / 256 + 1, 256, 0, stream>>>(
        toks, Wk, Wv, Wo, Wq, evs, (const unsigned char*)ents,
        toks_bf, Wk_bf, Wv_bf, Wo_bf, Wq_bf, ev_bf, flag);
    proj_kernel<<<260, 256, 0, stream>>>(toks_bf, Wk_bf, Wv_bf, ev_bf, Wq_bf,
                                         bk, bv, bq, K_bf, Vt_bf, q_bf);
    scores_mfma<<<64, 256, 0, stream>>>(q_bf, K_bf, S_bf);
    attn_out<<<256, 1024, 0, stream>>>(S_bf, Vt_bf, ents, flag, Wo_bf, bo, (float*)d_out);
}